// Round 3
// baseline (221.632 us; speedup 1.0000x reference)
//
#include <hip/hip_runtime.h>
#include <hip/hip_bf16.h>
#include <stdint.h>

// MMD loss: L=8192 total rows, D=1024, n=4096 per half.
// result = (Sum_ss + Sum_tt - Sum_cross) / (5 n^2), bandwidth closed-form:
//   sum(d2) = 2L*sum(sq) - 2*||colsum||^2   (diagonal contributes exactly 0)

#define L_TOTAL 8192
#define D_FEAT  1024
#define N_HALF  4096
#define TILE    128
#define TTILES  64                      // L/TILE
#define NBLK    (TTILES*(TTILES+1)/2)   // 2080 lower-triangle tiles (2080%8==0)
#define BK      64                      // K-step: 128B rows -> full 8-slot swizzle

typedef __bf16 bf16_t;
typedef __bf16 bf16x4_t __attribute__((ext_vector_type(4)));
typedef __bf16 bf16x8_t __attribute__((ext_vector_type(8)));
typedef float  f32x4_t  __attribute__((ext_vector_type(4)));

// workspace layout (bytes)
#define XB_OFF   0                              // bf16 X [8192][1024] = 16 MB
#define SQ_OFF   (L_TOTAL * D_FEAT * 2)         // f32 sq[8192]
#define COL_OFF  (SQ_OFF + L_TOTAL * 4)         // f32 colsum[1024]
#define SACC_OFF (COL_OFF + D_FEAT * 4)         // double S_acc
#define C1_OFF   (SACC_OFF + 8)                 // float c1 = -log2e/(16*bw)

__device__ __forceinline__ void async_ld16(void* lds, const void* g) {
  auto ldsp = (__attribute__((address_space(3))) void*)(uintptr_t)lds;
  auto gp   = (const __attribute__((address_space(1))) void*)(uintptr_t)g;
  __builtin_amdgcn_global_load_lds(gp, ldsp, 16, 0, 0);  // lane i -> base + i*16
}

// --- kernel 0: zero the atomic targets (ws is re-poisoned 0xAA every launch)
extern "C" __global__ __launch_bounds__(256) void k_zero(
    float* __restrict__ colsum, double* __restrict__ S_acc)
{
  const int tid = threadIdx.x;
  for (int c = tid; c < D_FEAT; c += 256) colsum[c] = 0.f;
  if (tid == 0) *S_acc = 0.0;
}

// --- kernel 1 (fused, coalesced): cast to bf16 + per-row sum-of-squares of the
//     bf16-rounded values + fp32 column sums of the ORIGINAL values.
//     256 blocks x 256 threads; wave handles 8 rows; lane-contiguous float4s.
extern "C" __global__ __launch_bounds__(256) void k_prep(
    const float* __restrict__ src, const float* __restrict__ tgt,
    bf16_t* __restrict__ Xb, float* __restrict__ sq, float* __restrict__ colsum)
{
  __shared__ float cs[4][D_FEAT];               // per-wave colsum partials, 16KB
  const int tid  = threadIdx.x;
  const int lane = tid & 63;
  const int w    = tid >> 6;
  const int rbase = blockIdx.x * 32 + w * 8;

  float csp[16];
  #pragma unroll
  for (int j = 0; j < 16; ++j) csp[j] = 0.f;

  for (int i = 0; i < 8; ++i) {
    const int row = rbase + i;
    const float* xr = (row < N_HALF) ? (src + (size_t)row * D_FEAT)
                                     : (tgt + (size_t)(row - N_HALF) * D_FEAT);
    float s = 0.f;
    #pragma unroll
    for (int q = 0; q < 4; ++q) {
      const float4 v = ((const float4*)xr)[q * 64 + lane];   // coalesced 16B/lane
      bf16x4_t bv;
      bv[0] = (bf16_t)v.x; bv[1] = (bf16_t)v.y; bv[2] = (bf16_t)v.z; bv[3] = (bf16_t)v.w;
      *(bf16x4_t*)(Xb + (size_t)row * D_FEAT + (q * 64 + lane) * 4) = bv;
      const float g0 = (float)bv[0], g1 = (float)bv[1], g2 = (float)bv[2], g3 = (float)bv[3];
      s += g0 * g0 + g1 * g1 + g2 * g2 + g3 * g3;
      csp[q * 4 + 0] += v.x; csp[q * 4 + 1] += v.y;
      csp[q * 4 + 2] += v.z; csp[q * 4 + 3] += v.w;
    }
    #pragma unroll
    for (int off = 32; off > 0; off >>= 1) s += __shfl_down(s, off);
    if (lane == 0) sq[row] = s;
  }

  #pragma unroll
  for (int q = 0; q < 4; ++q) {
    float4 v4 = make_float4(csp[q*4+0], csp[q*4+1], csp[q*4+2], csp[q*4+3]);
    *(float4*)&cs[w][(q * 64 + lane) * 4] = v4;
  }
  __syncthreads();
  #pragma unroll
  for (int k = 0; k < 4; ++k) {
    const int c = tid * 4 + k;
    atomicAdd(&colsum[c], cs[0][c] + cs[1][c] + cs[2][c] + cs[3][c]);
  }
}

// --- kernel 2: c1 = -log2(e) / (16 * bw),  bw = (sum(d2)/(L^2-L)) / 4
extern "C" __global__ __launch_bounds__(1024) void k_bw(
    const float* __restrict__ sq, const float* __restrict__ colsum,
    float* __restrict__ c1out)
{
  const int tid = threadIdx.x;
  double t = 0.0;
  for (int i = tid; i < L_TOTAL; i += 1024) t += (double)sq[i];
  t *= 2.0 * (double)L_TOTAL;
  if (tid < D_FEAT) { double v = colsum[tid]; t -= 2.0 * v * v; }
  __shared__ double red[1024];
  red[tid] = t;
  __syncthreads();
  for (int off = 512; off > 0; off >>= 1) {
    if (tid < off) red[tid] += red[tid + off];
    __syncthreads();
  }
  if (tid == 0) {
    double bw = red[0] / ((double)L_TOTAL * (double)L_TOTAL - (double)L_TOTAL);
    bw = bw / 4.0;                               // KERNEL_MUL ** (KERNEL_NUM//2)
    *c1out = (float)(-1.4426950408889634 / (16.0 * bw));
  }
}

// --- kernel 3: fused Gram-MFMA + RBF + signed reduction, lower-triangle tiles.
//     BK=64, XOR-swizzled LDS; ALL swizzle math hoisted out of the k-loop:
//     r&7 == lane&7 (m*16, wr*64 are 0 mod 8) so the XOR is lane-constant, and
//     the kk=1 slot base is just base^64. In-loop LDS reads = ds_read_b128 with
//     immediate offsets only.
extern "C" __global__ __launch_bounds__(256) void k_mmd(
    const bf16_t* __restrict__ Xb, const float* __restrict__ sq,
    const float* __restrict__ c1ptr, double* __restrict__ S_acc)
{
  __shared__ __align__(16) char smem[2 * TILE * BK * 2];   // 32768 B: As | Bs
  bf16_t* As = (bf16_t*)smem;
  bf16_t* Bs = (bf16_t*)(smem + TILE * BK * 2);

  // XCD-aware bijective swizzle (NBLK % 8 == 0)
  const int b = (blockIdx.x & 7) * (NBLK / 8) + (blockIdx.x >> 3);
  int ti = (int)((sqrtf(8.f * (float)b + 1.f) - 1.f) * 0.5f);
  while ((ti + 1) * (ti + 2) / 2 <= b) ++ti;
  while (ti * (ti + 1) / 2 > b) --ti;
  const int tj = b - ti * (ti + 1) / 2;          // tj <= ti
  const int row0 = ti * TILE, col0 = tj * TILE;

  const int tid  = threadIdx.x;
  const int lane = tid & 63;
  const int w    = tid >> 6;         // 4 waves, 2x2 over the 128x128 tile
  const int wr   = w >> 1, wc = w & 1;

  // staging source offsets (elements), swizzle pre-permuted on the global side
  const int srow = lane >> 3;                    // 0..7
  const int scol = ((lane & 7) ^ srow) * 8;      // involution: src col for phys slot lane&7
  uint32_t offA[4], offB[4];
  #pragma unroll
  for (int q = 0; q < 4; ++q) {
    const int ch = w * 4 + q;
    offA[q] = (uint32_t)(row0 + ch * 8 + srow) * D_FEAT + scol;
    offB[q] = (uint32_t)(col0 + ch * 8 + srow) * D_FEAT + scol;
  }

  // fragment-read byte bases (XOR hoisted; kk=1 base = kk=0 base ^ 64)
  const int x = lane >> 4, y = lane & 7, rlo = lane & 15;
  const int baA0 = (wr * 64 + rlo) * (BK * 2) + ((x ^ y) * 16);
  const int baB0 = (wc * 64 + rlo) * (BK * 2) + ((x ^ y) * 16);
  const int baA1 = baA0 ^ 64;
  const int baB1 = baB0 ^ 64;
  const char* Ac = (const char*)As;
  const char* Bc = (const char*)Bs;

  f32x4_t acc[4][4] = {};            // wave computes 64x64 = 4x4 frags of 16x16

  for (int k0 = 0; k0 < D_FEAT; k0 += BK) {
    #pragma unroll
    for (int q = 0; q < 4; ++q) {
      async_ld16(&As[(w * 4 + q) * 512], Xb + offA[q] + k0);
      async_ld16(&Bs[(w * 4 + q) * 512], Xb + offB[q] + k0);
    }
    __syncthreads();                 // drains vmcnt -> tiles visible

    bf16x8_t af0[4], af1[4], bf0[4], bf1[4];
    #pragma unroll
    for (int m = 0; m < 4; ++m) {
      af0[m] = *(const bf16x8_t*)(Ac + baA0 + m * 2048);
      af1[m] = *(const bf16x8_t*)(Ac + baA1 + m * 2048);
    }
    #pragma unroll
    for (int n = 0; n < 4; ++n) {
      bf0[n] = *(const bf16x8_t*)(Bc + baB0 + n * 2048);
      bf1[n] = *(const bf16x8_t*)(Bc + baB1 + n * 2048);
    }
    #pragma unroll
    for (int m = 0; m < 4; ++m)
      #pragma unroll
      for (int n = 0; n < 4; ++n)
        acc[m][n] = __builtin_amdgcn_mfma_f32_16x16x32_bf16(af0[m], bf0[n], acc[m][n], 0, 0, 0);
    #pragma unroll
    for (int m = 0; m < 4; ++m)
      #pragma unroll
      for (int n = 0; n < 4; ++n)
        acc[m][n] = __builtin_amdgcn_mfma_f32_16x16x32_bf16(af1[m], bf1[n], acc[m][n], 0, 0, 0);
    __syncthreads();
  }

  // epilogue: d2 -> 5-scale RBF via 1 exp2 + 4 squarings; signed partial sum
  const float c1   = *c1ptr;                      // -log2e/(16*bw)
  const float sgn  = ((ti < TTILES / 2) == (tj < TTILES / 2)) ? 1.f : -1.f;
  const float wgt  = (ti == tj ? 1.f : 2.f) * sgn;
  float part = 0.f;
  const int colb = col0 + wc * 64 + rlo;
  const int rowb = row0 + wr * 64 + x * 4;   // C/D map: col=lane&15, row=(lane>>4)*4+reg
  #pragma unroll
  for (int m = 0; m < 4; ++m) {
    #pragma unroll
    for (int n = 0; n < 4; ++n) {
      const float sqj = sq[colb + n * 16];
      #pragma unroll
      for (int r = 0; r < 4; ++r) {
        const float sqi = sq[rowb + m * 16 + r];
        float d2 = fmaxf(sqi + sqj - 2.f * acc[m][n][r], 0.f);
        const float e  = __builtin_amdgcn_exp2f(d2 * c1);  // exp(-d2/(bw*16))
        const float e2 = e * e, e4 = e2 * e2, e8 = e4 * e4, e16 = e8 * e8;
        part += e + e2 + e4 + e8 + e16;
      }
    }
  }
  part *= wgt;

  #pragma unroll
  for (int off = 32; off > 0; off >>= 1) part += __shfl_down(part, off);
  float* red = (float*)smem;                 // As is dead past the last barrier
  __syncthreads();                           // (paranoia: all LDS reads done)
  if (lane == 0) red[w] = part;
  __syncthreads();
  if (tid == 0)
    atomicAdd(S_acc, (double)(red[0] + red[1] + red[2] + red[3]));
}

// --- kernel 4: finalize
extern "C" __global__ void k_fin(const double* __restrict__ S_acc, float* __restrict__ out)
{
  out[0] = (float)(*S_acc / (5.0 * (double)N_HALF * (double)N_HALF));
}

extern "C" void kernel_launch(void* const* d_in, const int* in_sizes, int n_in,
                              void* d_out, int out_size, void* d_ws, size_t ws_size,
                              hipStream_t stream) {
  const float* src = (const float*)d_in[0];
  const float* tgt = (const float*)d_in[1];
  float* out = (float*)d_out;
  char* ws = (char*)d_ws;
  bf16_t* Xb     = (bf16_t*)(ws + XB_OFF);
  float*  sq     = (float*)(ws + SQ_OFF);
  float*  colsum = (float*)(ws + COL_OFF);
  double* S_acc  = (double*)(ws + SACC_OFF);
  float*  c1     = (float*)(ws + C1_OFF);

  k_zero<<<1, 256, 0, stream>>>(colsum, S_acc);
  k_prep<<<256, 256, 0, stream>>>(src, tgt, Xb, sq, colsum);
  k_bw  <<<1, 1024, 0, stream>>>(sq, colsum, c1);
  k_mmd <<<NBLK, 256, 0, stream>>>(Xb, sq, c1, S_acc);
  k_fin <<<1, 1, 0, stream>>>(S_acc, out);
}